// Round 2
// 291.563 us; speedup vs baseline: 1.0224x; 1.0224x over previous
//
#include <hip/hip_runtime.h>

// Problem constants: N=50000, E=800000, IN=128, HID=64, OUT=40
#define HID 64
#define JK_DIM 192
#define OUT_DIM 40
#define A_PITCH 68     // gemm A-tile pitch: 16B aligned, max 2-way bank alias
#define W_PITCH 196    // final_gemm LDS pitch for Wt rows
#define FG_PITCH 44    // final_gemm epilogue staging pitch

// bf16 helpers (RNE pack; packed-word unpack via shift/mask)
__device__ inline unsigned short f2b(float f) {
    unsigned u = __float_as_uint(f);
    unsigned r = u + 0x7FFF + ((u >> 16) & 1);
    return (unsigned short)(r >> 16);
}
__device__ inline float b2f(unsigned short u) {
    return __uint_as_float(((unsigned)u) << 16);
}
__device__ inline float blo(unsigned u) { return __uint_as_float(u << 16); }
__device__ inline float bhi(unsigned u) { return __uint_as_float(u & 0xFFFF0000u); }
__device__ inline unsigned pack2(float a, float b) {
    return (unsigned)f2b(a) | ((unsigned)f2b(b) << 16);
}

// ---------------------------------------------------------------------------
// prep: zero deg + transpose Wlin[192,40] -> Wt[40,192] in one launch.
// ---------------------------------------------------------------------------
__global__ __launch_bounds__(256) void prep(int* __restrict__ deg, int n,
                                            const float* __restrict__ W,
                                            float* __restrict__ Wt) {
    int i = blockIdx.x * 256 + threadIdx.x;
    if (i < n) deg[i] = 0;
    if (i < JK_DIM * OUT_DIM) {
        int k = i / OUT_DIM;
        int c = i - k * OUT_DIM;
        Wt[c * JK_DIM + k] = W[i];
    }
}

// ---------------------------------------------------------------------------
// XCD-partitioned histogram. Also records each edge's arrival rank
// (the atomic's old value) so the CSR fill needs no atomics at all.
// ---------------------------------------------------------------------------
__global__ __launch_bounds__(256) void hist_dst(const int* __restrict__ dst,
                                                int* __restrict__ deg,
                                                unsigned short* __restrict__ rank,
                                                int E, int part) {
    int p = blockIdx.x & 7;
    int bid = blockIdx.x >> 3;
    int nblk = gridDim.x >> 3;
    int lo = p * part, hi = lo + part;
    int E4 = E >> 2;
    for (int q = bid * 256 + threadIdx.x; q < E4; q += nblk * 256) {
        int4 d4 = ((const int4*)dst)[q];
        int e = q * 4;
        if (d4.x >= lo && d4.x < hi) rank[e + 0] = (unsigned short)atomicAdd(&deg[d4.x], 1);
        if (d4.y >= lo && d4.y < hi) rank[e + 1] = (unsigned short)atomicAdd(&deg[d4.y], 1);
        if (d4.z >= lo && d4.z < hi) rank[e + 2] = (unsigned short)atomicAdd(&deg[d4.z], 1);
        if (d4.w >= lo && d4.w < hi) rank[e + 3] = (unsigned short)atomicAdd(&deg[d4.w], 1);
    }
    if (bid == 0 && threadIdx.x < (E & 3)) {
        int e = (E & ~3) + threadIdx.x;
        int d = dst[e];
        if (d >= lo && d < hi) rank[e] = (unsigned short)atomicAdd(&deg[d], 1);
    }
}

__global__ __launch_bounds__(256) void scan_a(const int* __restrict__ deg,
                                              int* __restrict__ off,
                                              int* __restrict__ bsum, int n) {
    __shared__ int tmp[256];
    int i = blockIdx.x * 256 + threadIdx.x;
    int v = (i < n) ? deg[i] : 0;
    tmp[threadIdx.x] = v;
    __syncthreads();
    for (int d = 1; d < 256; d <<= 1) {
        int t = (threadIdx.x >= d) ? tmp[threadIdx.x - d] : 0;
        __syncthreads();
        tmp[threadIdx.x] += t;
        __syncthreads();
    }
    if (i < n) off[i] = tmp[threadIdx.x] - v;
    if (threadIdx.x == 255) bsum[blockIdx.x] = tmp[255];
}

__global__ __launch_bounds__(256) void scan_b(int* __restrict__ bsum, int nblk) {
    __shared__ int tmp[256];
    int v = (threadIdx.x < nblk) ? bsum[threadIdx.x] : 0;
    tmp[threadIdx.x] = v;
    __syncthreads();
    for (int d = 1; d < 256; d <<= 1) {
        int t = (threadIdx.x >= d) ? tmp[threadIdx.x - d] : 0;
        __syncthreads();
        tmp[threadIdx.x] += t;
        __syncthreads();
    }
    if (threadIdx.x < nblk) bsum[threadIdx.x] = tmp[threadIdx.x] - v;
}

__global__ __launch_bounds__(256) void scan_c(int* __restrict__ off,
                                              const int* __restrict__ bsum, int n) {
    int i = blockIdx.x * 256 + threadIdx.x;
    if (i >= n) return;
    off[i] += bsum[blockIdx.x];
}

// ---------------------------------------------------------------------------
// FUSED: atomic-free CSR fill + layer-1 GEMM.
// Even blocks -> one 64-row GEMM tile (800 slots, 782 used);
// odd blocks  -> fill work: one int4 edge-group per thread, single pass,
//                slot = off[dst] + rank  (pure gather/scatter, no atomics,
//                no 8x partition rescan of dst).
// ---------------------------------------------------------------------------
__global__ __launch_bounds__(256) void fill_and_gemm(
        const int* __restrict__ src, const int* __restrict__ dst,
        const float* __restrict__ ew, const int* __restrict__ off,
        const unsigned short* __restrict__ rank,
        unsigned* __restrict__ ecsr, int E,
        const float* __restrict__ x, const float* __restrict__ W1,
        unsigned short* __restrict__ linb, int n) {
    __shared__ float As[64 * A_PITCH];
    __shared__ float Ws[64 * HID];
    if (blockIdx.x & 1) {
        // ---- fill branch: no atomics, one int4 per thread ----
        int f = blockIdx.x >> 1;
        int q = f * 256 + threadIdx.x;
        int E4 = E >> 2;
        if (q < E4) {
            int4 d4 = ((const int4*)dst)[q];
            int4 s4 = ((const int4*)src)[q];
            float4 wv = ((const float4*)ew)[q];
            ushort4 r4 = ((const ushort4*)rank)[q];
            ecsr[off[d4.x] + r4.x] = (unsigned)s4.x | ((unsigned)f2b(wv.x) << 16);
            ecsr[off[d4.y] + r4.y] = (unsigned)s4.y | ((unsigned)f2b(wv.y) << 16);
            ecsr[off[d4.z] + r4.z] = (unsigned)s4.z | ((unsigned)f2b(wv.z) << 16);
            ecsr[off[d4.w] + r4.w] = (unsigned)s4.w | ((unsigned)f2b(wv.w) << 16);
        }
        if (f == 0 && threadIdx.x < (E & 3)) {
            int e = (E & ~3) + threadIdx.x;
            int d = dst[e];
            ecsr[off[d] + rank[e]] = (unsigned)src[e] | ((unsigned)f2b(ew[e]) << 16);
        }
        return;
    }
    // ---- gemm branch: lin(bf16) = x[64x128](f32) @ W1[128x64] ----
    int g = blockIdx.x >> 1;
    int row0 = g * 64;
    if (row0 >= n) return;
    int tid = threadIdx.x;
    int rg = tid >> 4;
    int cgrp = tid & 15;
    int c0 = cgrp * 4;

    float acc[4][4] = {{0.f}};
    for (int kb = 0; kb < 128; kb += 64) {
        for (int i = tid; i < 64 * 16; i += 256) {
            int r = i >> 4;
            int c4 = (i & 15) * 4;
            int grow = row0 + r;
            if (grow >= n) grow = n - 1;
            float4 v = *(const float4*)(x + (long)grow * 128 + kb + c4);
            *(float4*)(As + r * A_PITCH + c4) = v;
        }
        for (int i = tid; i < 64 * 16; i += 256) {
            int k = i >> 4;
            int c4 = (i & 15) * 4;
            *(float4*)(Ws + k * HID + c4) = *(const float4*)(W1 + (long)(kb + k) * HID + c4);
        }
        __syncthreads();
#pragma unroll 4
        for (int k = 0; k < 64; k += 4) {
            float4 w0 = *(const float4*)(Ws + (k + 0) * HID + c0);
            float4 w1 = *(const float4*)(Ws + (k + 1) * HID + c0);
            float4 w2 = *(const float4*)(Ws + (k + 2) * HID + c0);
            float4 w3 = *(const float4*)(Ws + (k + 3) * HID + c0);
#pragma unroll
            for (int r = 0; r < 4; ++r) {
                float4 a = *(const float4*)(As + (rg * 4 + r) * A_PITCH + k);
                acc[r][0] += a.x * w0.x + a.y * w1.x + a.z * w2.x + a.w * w3.x;
                acc[r][1] += a.x * w0.y + a.y * w1.y + a.z * w2.y + a.w * w3.y;
                acc[r][2] += a.x * w0.z + a.y * w1.z + a.z * w2.z + a.w * w3.z;
                acc[r][3] += a.x * w0.w + a.y * w1.w + a.z * w2.w + a.w * w3.w;
            }
        }
        __syncthreads();
    }
#pragma unroll
    for (int r = 0; r < 4; ++r) {
        int grow = row0 + rg * 4 + r;
        if (grow < n) {
            ushort4 o;
            o.x = f2b(acc[r][0]);
            o.y = f2b(acc[r][1]);
            o.z = f2b(acc[r][2]);
            o.w = f2b(acc[r][3]);
            *(ushort4*)(linb + (long)grow * HID + c0) = o;
        }
    }
}

// ---------------------------------------------------------------------------
// Layers 2/3 GEMM: lin(bf16) = h[64 x 64](bf16, row stride JK_DIM) @ W[64x64].
// ---------------------------------------------------------------------------
__global__ __launch_bounds__(256) void gemm_b16in(const unsigned short* __restrict__ h,
                                                  const float* __restrict__ W,
                                                  unsigned short* __restrict__ outb,
                                                  int n) {
    __shared__ float As[64 * A_PITCH];
    __shared__ float Ws[64 * HID];
    int tid = threadIdx.x;
    int rg = tid >> 4;
    int cgrp = tid & 15;
    int c0 = cgrp * 4;
    int row0 = blockIdx.x * 64;
    if (row0 >= n) return;

    for (int i = tid; i < 64 * 8; i += 256) {
        int r = i >> 3;
        int q = (i & 7) * 8;
        int grow = row0 + r;
        if (grow >= n) grow = n - 1;
        uint4 u = *(const uint4*)(h + (long)grow * JK_DIM + q);
        float4 lo4 = make_float4(blo(u.x), bhi(u.x), blo(u.y), bhi(u.y));
        float4 hi4 = make_float4(blo(u.z), bhi(u.z), blo(u.w), bhi(u.w));
        *(float4*)(As + r * A_PITCH + q) = lo4;
        *(float4*)(As + r * A_PITCH + q + 4) = hi4;
    }
    for (int i = tid; i < 64 * 16; i += 256) {
        int k = i >> 4;
        int c4 = (i & 15) * 4;
        *(float4*)(Ws + k * HID + c4) = *(const float4*)(W + (long)k * HID + c4);
    }
    __syncthreads();

    float acc[4][4] = {{0.f}};
#pragma unroll 4
    for (int k = 0; k < 64; k += 4) {
        float4 w0 = *(const float4*)(Ws + (k + 0) * HID + c0);
        float4 w1 = *(const float4*)(Ws + (k + 1) * HID + c0);
        float4 w2 = *(const float4*)(Ws + (k + 2) * HID + c0);
        float4 w3 = *(const float4*)(Ws + (k + 3) * HID + c0);
#pragma unroll
        for (int r = 0; r < 4; ++r) {
            float4 a = *(const float4*)(As + (rg * 4 + r) * A_PITCH + k);
            acc[r][0] += a.x * w0.x + a.y * w1.x + a.z * w2.x + a.w * w3.x;
            acc[r][1] += a.x * w0.y + a.y * w1.y + a.z * w2.y + a.w * w3.y;
            acc[r][2] += a.x * w0.z + a.y * w1.z + a.z * w2.z + a.w * w3.z;
            acc[r][3] += a.x * w0.w + a.y * w1.w + a.z * w2.w + a.w * w3.w;
        }
    }
#pragma unroll
    for (int r = 0; r < 4; ++r) {
        int grow = row0 + rg * 4 + r;
        if (grow < n) {
            ushort4 o;
            o.x = f2b(acc[r][0]);
            o.y = f2b(acc[r][1]);
            o.z = f2b(acc[r][2]);
            o.w = f2b(acc[r][3]);
            *(ushort4*)(outb + (long)grow * HID + c0) = o;
        }
    }
}

// ---------------------------------------------------------------------------
// Aggregate + bias + ReLU. One 8-lane group per node (8 nodes/wave); lane
// covers 16B (8 bf16 cols). 8-stream software pipeline: 64 independent
// gathers in flight per wave. Output row written bf16 into hcat col block.
// ---------------------------------------------------------------------------
__global__ __launch_bounds__(256) void aggregate(const unsigned short* __restrict__ linb,
                                                 const unsigned* __restrict__ ecsr,
                                                 const int* __restrict__ off,
                                                 const int* __restrict__ deg,
                                                 const float* __restrict__ bias,
                                                 unsigned short* __restrict__ hout, int n) {
    int cl = threadIdx.x & 7;       // 16B slice within the 128B bf16 row
    float4 bLo = *(const float4*)(bias + cl * 8);
    float4 bHi = *(const float4*)(bias + cl * 8 + 4);
    int grp = (blockIdx.x * 256 + threadIdx.x) >> 3;
    int ngrp = (gridDim.x * 256) >> 3;
    for (int node = grp; node < n; node += ngrp) {
        int start = off[node];
        int cnt = deg[node];
        float acc[8];
#pragma unroll
        for (int i = 0; i < 8; ++i) acc[i] = 0.f;

        int s[8];
        float w[8];
#pragma unroll
        for (int t = 0; t < 8; ++t) {
            s[t] = 0; w[t] = 0.f;
            if (t < cnt) {
                unsigned m = ecsr[start + t];
                s[t] = (int)(m & 0xFFFFu);
                w[t] = b2f((unsigned short)(m >> 16));
            }
        }
        for (int bb = 0; bb < cnt; bb += 8) {
            int s2[8];
            float w2[8];
#pragma unroll
            for (int t = 0; t < 8; ++t) {
                int e = bb + 8 + t;
                s2[t] = 0; w2[t] = 0.f;
                if (e < cnt) {
                    unsigned m = ecsr[start + e];
                    s2[t] = (int)(m & 0xFFFFu);
                    w2[t] = b2f((unsigned short)(m >> 16));
                }
            }
            uint4 u[8];
#pragma unroll
            for (int t = 0; t < 8; ++t)
                u[t] = *(const uint4*)(linb + (long)s[t] * HID + cl * 8);
#pragma unroll
            for (int t = 0; t < 8; ++t) {
                acc[0] += blo(u[t].x) * w[t];
                acc[1] += bhi(u[t].x) * w[t];
                acc[2] += blo(u[t].y) * w[t];
                acc[3] += bhi(u[t].y) * w[t];
                acc[4] += blo(u[t].z) * w[t];
                acc[5] += bhi(u[t].z) * w[t];
                acc[6] += blo(u[t].w) * w[t];
                acc[7] += bhi(u[t].w) * w[t];
            }
#pragma unroll
            for (int t = 0; t < 8; ++t) { s[t] = s2[t]; w[t] = w2[t]; }
        }

        uint4 o;
        o.x = pack2(fmaxf(acc[0] + bLo.x, 0.f), fmaxf(acc[1] + bLo.y, 0.f));
        o.y = pack2(fmaxf(acc[2] + bLo.z, 0.f), fmaxf(acc[3] + bLo.w, 0.f));
        o.z = pack2(fmaxf(acc[4] + bHi.x, 0.f), fmaxf(acc[5] + bHi.y, 0.f));
        o.w = pack2(fmaxf(acc[6] + bHi.z, 0.f), fmaxf(acc[7] + bHi.w, 0.f));
        *(uint4*)(hout + (long)node * JK_DIM + cl * 8) = o;
    }
}

// ---------------------------------------------------------------------------
// Final: out[n,40](f32) = hcat[n,192](bf16) @ Wlin[192,40] + blin.
// 64-row tile per 256-thread block; thread = 2 rows x 5 cols; Wt in LDS at
// pitch 196; pool reused as epilogue staging for coalesced float4 stores.
// ---------------------------------------------------------------------------
__global__ __launch_bounds__(256) void final_gemm(const unsigned short* __restrict__ hcat,
                                                  const float* __restrict__ Wt,
                                                  const float* __restrict__ b,
                                                  float* __restrict__ out, int n) {
    __shared__ float pool[OUT_DIM * W_PITCH];  // 31360 B
    int tid = threadIdx.x;
    for (int i = tid; i < OUT_DIM * 48; i += 256) {
        int c = i / 48;
        int q = (i - c * 48) * 4;
        *(float4*)(pool + c * W_PITCH + q) = *(const float4*)(Wt + (long)c * JK_DIM + q);
    }
    __syncthreads();

    int rg = tid >> 3;
    int cg = tid & 7;
    int c0 = cg * 5;
    int row0 = blockIdx.x * 64;
    int r0 = row0 + rg * 2;
    int ra = r0 < n ? r0 : n - 1;
    int rb = r0 + 1 < n ? r0 + 1 : n - 1;
    const unsigned short* ha = hcat + (long)ra * JK_DIM;
    const unsigned short* hb = hcat + (long)rb * JK_DIM;

    float acc[2][5];
#pragma unroll
    for (int r = 0; r < 2; ++r)
#pragma unroll
        for (int i = 0; i < 5; ++i) acc[r][i] = 0.f;

#pragma unroll 4
    for (int k = 0; k < JK_DIM; k += 4) {
        uint2 ua = *(const uint2*)(ha + k);
        uint2 ub = *(const uint2*)(hb + k);
        float4 va = make_float4(blo(ua.x), bhi(ua.x), blo(ua.y), bhi(ua.y));
        float4 vb = make_float4(blo(ub.x), bhi(ub.x), blo(ub.y), bhi(ub.y));
        float4 w0 = *(const float4*)(pool + (c0 + 0) * W_PITCH + k);
        float4 w1 = *(const float4*)(pool + (c0 + 1) * W_PITCH + k);
        float4 w2 = *(const float4*)(pool + (c0 + 2) * W_PITCH + k);
        float4 w3 = *(const float4*)(pool + (c0 + 3) * W_PITCH + k);
        float4 w4 = *(const float4*)(pool + (c0 + 4) * W_PITCH + k);
        acc[0][0] += va.x * w0.x + va.y * w0.y + va.z * w0.z + va.w * w0.w;
        acc[0][1] += va.x * w1.x + va.y * w1.y + va.z * w1.z + va.w * w1.w;
        acc[0][2] += va.x * w2.x + va.y * w2.y + va.z * w2.z + va.w * w2.w;
        acc[0][3] += va.x * w3.x + va.y * w3.y + va.z * w3.z + va.w * w3.w;
        acc[0][4] += va.x * w4.x + va.y * w4.y + va.z * w4.z + va.w * w4.w;
        acc[1][0] += vb.x * w0.x + vb.y * w0.y + vb.z * w0.z + vb.w * w0.w;
        acc[1][1] += vb.x * w1.x + vb.y * w1.y + vb.z * w1.z + vb.w * w1.w;
        acc[1][2] += vb.x * w2.x + vb.y * w2.y + vb.z * w2.z + vb.w * w2.w;
        acc[1][3] += vb.x * w3.x + vb.y * w3.y + vb.z * w3.z + vb.w * w3.w;
        acc[1][4] += vb.x * w4.x + vb.y * w4.y + vb.z * w4.z + vb.w * w4.w;
    }

    __syncthreads();
#pragma unroll
    for (int r = 0; r < 2; ++r)
#pragma unroll
        for (int i = 0; i < 5; ++i)
            pool[(rg * 2 + r) * FG_PITCH + c0 + i] = acc[r][i] + b[c0 + i];
    __syncthreads();

    if (row0 + 64 <= n) {
        for (int i = tid; i < 64 * OUT_DIM / 4; i += 256) {
            int f = i * 4;
            int row = f / OUT_DIM;
            int col = f - row * OUT_DIM;
            *(float4*)(out + (long)(row0 + row) * OUT_DIM + col) =
                *(const float4*)(pool + row * FG_PITCH + col);
        }
    } else {
        for (int i = tid; i < 64 * OUT_DIM; i += 256) {
            int row = i / OUT_DIM;
            int col = i - row * OUT_DIM;
            if (row0 + row < n)
                out[(long)(row0 + row) * OUT_DIM + col] = pool[row * FG_PITCH + col];
        }
    }
}

// ---------------------------------------------------------------------------
extern "C" void kernel_launch(void* const* d_in, const int* in_sizes, int n_in,
                              void* d_out, int out_size, void* d_ws, size_t ws_size,
                              hipStream_t stream) {
    const float* x    = (const float*)d_in[0];
    const int*   ei   = (const int*)d_in[1];
    const float* ew   = (const float*)d_in[2];
    const float* W1   = (const float*)d_in[3];
    const float* b1   = (const float*)d_in[4];
    const float* W2   = (const float*)d_in[5];
    const float* b2   = (const float*)d_in[6];
    const float* W3   = (const float*)d_in[7];
    const float* b3   = (const float*)d_in[8];
    const float* Wlin = (const float*)d_in[9];
    const float* blin = (const float*)d_in[10];
    float* out = (float*)d_out;

    const int N = in_sizes[0] / 128;   // 50000
    const int E = in_sizes[2];         // 800000
    const int* src = ei;
    const int* dst = ei + E;
    const int PART = (N + 7) / 8;      // 6250 nodes per XCD partition

    // Workspace: linb(bf16) | hcatb(bf16) | deg,off [N] | bsum | Wt | ecsr
    // rank[E] (ushort) ALIASES the hcatb region: rank is dead after
    // fill_and_gemm; hcatb is first written by the layer-1 aggregate, which
    // is stream-ordered after fill_and_gemm. Keeps total ws <= round-0 size.
    char* wsb = (char*)d_ws;
    unsigned short* linb  = (unsigned short*)wsb;   wsb += (long)N * HID * 2;
    unsigned short* hcatb = (unsigned short*)wsb;   wsb += (long)N * JK_DIM * 2;
    int* deg    = (int*)wsb;                        wsb += (long)N * 4;
    int* off    = (int*)wsb;                        wsb += (long)N * 4;
    int* bsum   = (int*)wsb;                        wsb += 256 * 4;
    float* Wt   = (float*)wsb;                      wsb += (long)JK_DIM * OUT_DIM * 4;
    unsigned* ecsr = (unsigned*)wsb;
    unsigned short* rank = hcatb;  // aliased; lifetime ends before aggregate #1

    dim3 blk(256);
    const int nblkN = (N + 255) / 256;     // 196
    dim3 gN(nblkN);
    dim3 gHist(8 * 104);                   // 8 partitions x 104 blocks
    dim3 gFG(1600);                        // interleaved gemm1(800) + fill(800)
    dim3 gGemm((N + 63) / 64);
    dim3 gAgg((N + 31) / 32);              // 8 nodes per wave
    dim3 gFin((N + 63) / 64);

    unsigned short* h1 = hcatb;            // columns [0,64)   of hcat[N,192]
    unsigned short* h2 = hcatb + HID;      // columns [64,128)
    unsigned short* h3 = hcatb + 2 * HID;  // columns [128,192)

    // ---- prep (zero deg + transpose Wlin), hist(+rank), scans ----
    prep<<<gN, blk, 0, stream>>>(deg, N, Wlin, Wt);
    hist_dst<<<gHist, blk, 0, stream>>>(dst, deg, rank, E, PART);
    scan_a<<<gN, blk, 0, stream>>>(deg, off, bsum, N);
    scan_b<<<1, blk, 0, stream>>>(bsum, nblkN);
    scan_c<<<gN, blk, 0, stream>>>(off, bsum, N);

    // ---- fused atomic-free CSR fill + layer-1 GEMM ----
    fill_and_gemm<<<gFG, blk, 0, stream>>>(src, dst, ew, off, rank, ecsr, E,
                                           x, W1, linb, N);
    aggregate<<<gAgg, blk, 0, stream>>>(linb, ecsr, off, deg, b1, h1, N);

    // ---- layer 2 (K=64, bf16 input from hcat col block) ----
    gemm_b16in<<<gGemm, blk, 0, stream>>>(h1, W2, linb, N);
    aggregate<<<gAgg, blk, 0, stream>>>(linb, ecsr, off, deg, b2, h2, N);

    // ---- layer 3 ----
    gemm_b16in<<<gGemm, blk, 0, stream>>>(h2, W3, linb, N);
    aggregate<<<gAgg, blk, 0, stream>>>(linb, ecsr, off, deg, b3, h3, N);

    // ---- JK linear ----
    final_gemm<<<gFin, blk, 0, stream>>>(hcatb, Wt, blin, out, N);
}

// Round 3
// 282.080 us; speedup vs baseline: 1.0568x; 1.0336x over previous
//
#include <hip/hip_runtime.h>

// Problem constants: N=50000, E=800000, IN=128, HID=64, OUT=40
#define HID 64
#define JK_DIM 192
#define OUT_DIM 40
#define A_PITCH 68     // gemm A-tile pitch: 16B aligned, max 2-way bank alias
#define W_PITCH 196    // final_gemm LDS pitch for Wt rows
#define FG_PITCH 44    // final_gemm epilogue staging pitch

// bf16 helpers (RNE pack; packed-word unpack via shift/mask)
__device__ inline unsigned short f2b(float f) {
    unsigned u = __float_as_uint(f);
    unsigned r = u + 0x7FFF + ((u >> 16) & 1);
    return (unsigned short)(r >> 16);
}
__device__ inline float b2f(unsigned short u) {
    return __uint_as_float(((unsigned)u) << 16);
}
__device__ inline float blo(unsigned u) { return __uint_as_float(u << 16); }
__device__ inline float bhi(unsigned u) { return __uint_as_float(u & 0xFFFF0000u); }
__device__ inline unsigned pack2(float a, float b) {
    return (unsigned)f2b(a) | ((unsigned)f2b(b) << 16);
}

// ---------------------------------------------------------------------------
// prep: zero deg + transpose Wlin[192,40] -> Wt[40,192] in one launch.
// ---------------------------------------------------------------------------
__global__ __launch_bounds__(256) void prep(int* __restrict__ deg, int n,
                                            const float* __restrict__ W,
                                            float* __restrict__ Wt) {
    int i = blockIdx.x * 256 + threadIdx.x;
    if (i < n) deg[i] = 0;
    if (i < JK_DIM * OUT_DIM) {
        int k = i / OUT_DIM;
        int c = i - k * OUT_DIM;
        Wt[c * JK_DIM + k] = W[i];
    }
}

// ---------------------------------------------------------------------------
// XCD-partitioned histogram. Also records each edge's arrival rank
// (the atomic's old value) so the CSR fill needs no atomics at all.
// ---------------------------------------------------------------------------
__global__ __launch_bounds__(256) void hist_dst(const int* __restrict__ dst,
                                                int* __restrict__ deg,
                                                unsigned short* __restrict__ rank,
                                                int E, int part) {
    int p = blockIdx.x & 7;
    int bid = blockIdx.x >> 3;
    int nblk = gridDim.x >> 3;
    int lo = p * part, hi = lo + part;
    int E4 = E >> 2;
    for (int q = bid * 256 + threadIdx.x; q < E4; q += nblk * 256) {
        int4 d4 = ((const int4*)dst)[q];
        int e = q * 4;
        if (d4.x >= lo && d4.x < hi) rank[e + 0] = (unsigned short)atomicAdd(&deg[d4.x], 1);
        if (d4.y >= lo && d4.y < hi) rank[e + 1] = (unsigned short)atomicAdd(&deg[d4.y], 1);
        if (d4.z >= lo && d4.z < hi) rank[e + 2] = (unsigned short)atomicAdd(&deg[d4.z], 1);
        if (d4.w >= lo && d4.w < hi) rank[e + 3] = (unsigned short)atomicAdd(&deg[d4.w], 1);
    }
    if (bid == 0 && threadIdx.x < (E & 3)) {
        int e = (E & ~3) + threadIdx.x;
        int d = dst[e];
        if (d >= lo && d < hi) rank[e] = (unsigned short)atomicAdd(&deg[d], 1);
    }
}

__global__ __launch_bounds__(256) void scan_a(const int* __restrict__ deg,
                                              int* __restrict__ off,
                                              int* __restrict__ bsum, int n) {
    __shared__ int tmp[256];
    int i = blockIdx.x * 256 + threadIdx.x;
    int v = (i < n) ? deg[i] : 0;
    tmp[threadIdx.x] = v;
    __syncthreads();
    for (int d = 1; d < 256; d <<= 1) {
        int t = (threadIdx.x >= d) ? tmp[threadIdx.x - d] : 0;
        __syncthreads();
        tmp[threadIdx.x] += t;
        __syncthreads();
    }
    if (i < n) off[i] = tmp[threadIdx.x] - v;
    if (threadIdx.x == 255) bsum[blockIdx.x] = tmp[255];
}

__global__ __launch_bounds__(256) void scan_b(int* __restrict__ bsum, int nblk) {
    __shared__ int tmp[256];
    int v = (threadIdx.x < nblk) ? bsum[threadIdx.x] : 0;
    tmp[threadIdx.x] = v;
    __syncthreads();
    for (int d = 1; d < 256; d <<= 1) {
        int t = (threadIdx.x >= d) ? tmp[threadIdx.x - d] : 0;
        __syncthreads();
        tmp[threadIdx.x] += t;
        __syncthreads();
    }
    if (threadIdx.x < nblk) bsum[threadIdx.x] = tmp[threadIdx.x] - v;
}

__global__ __launch_bounds__(256) void scan_c(int* __restrict__ off,
                                              const int* __restrict__ bsum, int n) {
    int i = blockIdx.x * 256 + threadIdx.x;
    if (i >= n) return;
    off[i] += bsum[blockIdx.x];
}

// ---------------------------------------------------------------------------
// FUSED: atomic-free CSR fill + layer-1 GEMM.
// Blocks [0, nGemm)            -> one 64-row GEMM tile each.
// Blocks [nGemm, nGemm+nFill)  -> fill work: one int4 edge-group per thread,
//                                 slot = off[dst] + rank (no atomics).
// CONTIGUOUS ranges (not parity): XCD round-robin by blockIdx spreads each
// kind uniformly across all 8 XCDs. Parity split pinned all GEMM blocks to
// the 4 even XCDs (half-chip GEMM, idle odd XCDs).
// ---------------------------------------------------------------------------
__global__ __launch_bounds__(256) void fill_and_gemm(
        const int* __restrict__ src, const int* __restrict__ dst,
        const float* __restrict__ ew, const int* __restrict__ off,
        const unsigned short* __restrict__ rank,
        unsigned* __restrict__ ecsr, int E,
        const float* __restrict__ x, const float* __restrict__ W1,
        unsigned short* __restrict__ linb, int n, int nGemm) {
    __shared__ float As[64 * A_PITCH];
    __shared__ float Ws[64 * HID];
    if ((int)blockIdx.x >= nGemm) {
        // ---- fill branch: no atomics, one int4 per thread ----
        int f = blockIdx.x - nGemm;
        int q = f * 256 + threadIdx.x;
        int E4 = E >> 2;
        if (q < E4) {
            int4 d4 = ((const int4*)dst)[q];
            int4 s4 = ((const int4*)src)[q];
            float4 wv = ((const float4*)ew)[q];
            ushort4 r4 = ((const ushort4*)rank)[q];
            ecsr[off[d4.x] + r4.x] = (unsigned)s4.x | ((unsigned)f2b(wv.x) << 16);
            ecsr[off[d4.y] + r4.y] = (unsigned)s4.y | ((unsigned)f2b(wv.y) << 16);
            ecsr[off[d4.z] + r4.z] = (unsigned)s4.z | ((unsigned)f2b(wv.z) << 16);
            ecsr[off[d4.w] + r4.w] = (unsigned)s4.w | ((unsigned)f2b(wv.w) << 16);
        }
        if (f == 0 && threadIdx.x < (E & 3)) {
            int e = (E & ~3) + threadIdx.x;
            int d = dst[e];
            ecsr[off[d] + rank[e]] = (unsigned)src[e] | ((unsigned)f2b(ew[e]) << 16);
        }
        return;
    }
    // ---- gemm branch: lin(bf16) = x[64x128](f32) @ W1[128x64] ----
    int g = blockIdx.x;
    int row0 = g * 64;
    if (row0 >= n) return;
    int tid = threadIdx.x;
    int rg = tid >> 4;
    int cgrp = tid & 15;
    int c0 = cgrp * 4;

    float acc[4][4] = {{0.f}};
    for (int kb = 0; kb < 128; kb += 64) {
        for (int i = tid; i < 64 * 16; i += 256) {
            int r = i >> 4;
            int c4 = (i & 15) * 4;
            int grow = row0 + r;
            if (grow >= n) grow = n - 1;
            float4 v = *(const float4*)(x + (long)grow * 128 + kb + c4);
            *(float4*)(As + r * A_PITCH + c4) = v;
        }
        for (int i = tid; i < 64 * 16; i += 256) {
            int k = i >> 4;
            int c4 = (i & 15) * 4;
            *(float4*)(Ws + k * HID + c4) = *(const float4*)(W1 + (long)(kb + k) * HID + c4);
        }
        __syncthreads();
#pragma unroll 4
        for (int k = 0; k < 64; k += 4) {
            float4 w0 = *(const float4*)(Ws + (k + 0) * HID + c0);
            float4 w1 = *(const float4*)(Ws + (k + 1) * HID + c0);
            float4 w2 = *(const float4*)(Ws + (k + 2) * HID + c0);
            float4 w3 = *(const float4*)(Ws + (k + 3) * HID + c0);
#pragma unroll
            for (int r = 0; r < 4; ++r) {
                float4 a = *(const float4*)(As + (rg * 4 + r) * A_PITCH + k);
                acc[r][0] += a.x * w0.x + a.y * w1.x + a.z * w2.x + a.w * w3.x;
                acc[r][1] += a.x * w0.y + a.y * w1.y + a.z * w2.y + a.w * w3.y;
                acc[r][2] += a.x * w0.z + a.y * w1.z + a.z * w2.z + a.w * w3.z;
                acc[r][3] += a.x * w0.w + a.y * w1.w + a.z * w2.w + a.w * w3.w;
            }
        }
        __syncthreads();
    }
#pragma unroll
    for (int r = 0; r < 4; ++r) {
        int grow = row0 + rg * 4 + r;
        if (grow < n) {
            ushort4 o;
            o.x = f2b(acc[r][0]);
            o.y = f2b(acc[r][1]);
            o.z = f2b(acc[r][2]);
            o.w = f2b(acc[r][3]);
            *(ushort4*)(linb + (long)grow * HID + c0) = o;
        }
    }
}

// ---------------------------------------------------------------------------
// Layers 2/3 GEMM: lin(bf16) = h[64 x 64](bf16, row stride JK_DIM) @ W[64x64].
// ---------------------------------------------------------------------------
__global__ __launch_bounds__(256) void gemm_b16in(const unsigned short* __restrict__ h,
                                                  const float* __restrict__ W,
                                                  unsigned short* __restrict__ outb,
                                                  int n) {
    __shared__ float As[64 * A_PITCH];
    __shared__ float Ws[64 * HID];
    int tid = threadIdx.x;
    int rg = tid >> 4;
    int cgrp = tid & 15;
    int c0 = cgrp * 4;
    int row0 = blockIdx.x * 64;
    if (row0 >= n) return;

    for (int i = tid; i < 64 * 8; i += 256) {
        int r = i >> 3;
        int q = (i & 7) * 8;
        int grow = row0 + r;
        if (grow >= n) grow = n - 1;
        uint4 u = *(const uint4*)(h + (long)grow * JK_DIM + q);
        float4 lo4 = make_float4(blo(u.x), bhi(u.x), blo(u.y), bhi(u.y));
        float4 hi4 = make_float4(blo(u.z), bhi(u.z), blo(u.w), bhi(u.w));
        *(float4*)(As + r * A_PITCH + q) = lo4;
        *(float4*)(As + r * A_PITCH + q + 4) = hi4;
    }
    for (int i = tid; i < 64 * 16; i += 256) {
        int k = i >> 4;
        int c4 = (i & 15) * 4;
        *(float4*)(Ws + k * HID + c4) = *(const float4*)(W + (long)k * HID + c4);
    }
    __syncthreads();

    float acc[4][4] = {{0.f}};
#pragma unroll 4
    for (int k = 0; k < 64; k += 4) {
        float4 w0 = *(const float4*)(Ws + (k + 0) * HID + c0);
        float4 w1 = *(const float4*)(Ws + (k + 1) * HID + c0);
        float4 w2 = *(const float4*)(Ws + (k + 2) * HID + c0);
        float4 w3 = *(const float4*)(Ws + (k + 3) * HID + c0);
#pragma unroll
        for (int r = 0; r < 4; ++r) {
            float4 a = *(const float4*)(As + (rg * 4 + r) * A_PITCH + k);
            acc[r][0] += a.x * w0.x + a.y * w1.x + a.z * w2.x + a.w * w3.x;
            acc[r][1] += a.x * w0.y + a.y * w1.y + a.z * w2.y + a.w * w3.y;
            acc[r][2] += a.x * w0.z + a.y * w1.z + a.z * w2.z + a.w * w3.z;
            acc[r][3] += a.x * w0.w + a.y * w1.w + a.z * w2.w + a.w * w3.w;
        }
    }
#pragma unroll
    for (int r = 0; r < 4; ++r) {
        int grow = row0 + rg * 4 + r;
        if (grow < n) {
            ushort4 o;
            o.x = f2b(acc[r][0]);
            o.y = f2b(acc[r][1]);
            o.z = f2b(acc[r][2]);
            o.w = f2b(acc[r][3]);
            *(ushort4*)(outb + (long)grow * HID + c0) = o;
        }
    }
}

// ---------------------------------------------------------------------------
// Aggregate + bias + ReLU. One 8-lane group per node (8 nodes/wave); lane
// covers 16B (8 bf16 cols). 8-stream software pipeline: 64 independent
// gathers in flight per wave. Output row written bf16 into hcat col block.
// ---------------------------------------------------------------------------
__global__ __launch_bounds__(256) void aggregate(const unsigned short* __restrict__ linb,
                                                 const unsigned* __restrict__ ecsr,
                                                 const int* __restrict__ off,
                                                 const int* __restrict__ deg,
                                                 const float* __restrict__ bias,
                                                 unsigned short* __restrict__ hout, int n) {
    int cl = threadIdx.x & 7;       // 16B slice within the 128B bf16 row
    float4 bLo = *(const float4*)(bias + cl * 8);
    float4 bHi = *(const float4*)(bias + cl * 8 + 4);
    int grp = (blockIdx.x * 256 + threadIdx.x) >> 3;
    int ngrp = (gridDim.x * 256) >> 3;
    for (int node = grp; node < n; node += ngrp) {
        int start = off[node];
        int cnt = deg[node];
        float acc[8];
#pragma unroll
        for (int i = 0; i < 8; ++i) acc[i] = 0.f;

        int s[8];
        float w[8];
#pragma unroll
        for (int t = 0; t < 8; ++t) {
            s[t] = 0; w[t] = 0.f;
            if (t < cnt) {
                unsigned m = ecsr[start + t];
                s[t] = (int)(m & 0xFFFFu);
                w[t] = b2f((unsigned short)(m >> 16));
            }
        }
        for (int bb = 0; bb < cnt; bb += 8) {
            int s2[8];
            float w2[8];
#pragma unroll
            for (int t = 0; t < 8; ++t) {
                int e = bb + 8 + t;
                s2[t] = 0; w2[t] = 0.f;
                if (e < cnt) {
                    unsigned m = ecsr[start + e];
                    s2[t] = (int)(m & 0xFFFFu);
                    w2[t] = b2f((unsigned short)(m >> 16));
                }
            }
            uint4 u[8];
#pragma unroll
            for (int t = 0; t < 8; ++t)
                u[t] = *(const uint4*)(linb + (long)s[t] * HID + cl * 8);
#pragma unroll
            for (int t = 0; t < 8; ++t) {
                acc[0] += blo(u[t].x) * w[t];
                acc[1] += bhi(u[t].x) * w[t];
                acc[2] += blo(u[t].y) * w[t];
                acc[3] += bhi(u[t].y) * w[t];
                acc[4] += blo(u[t].z) * w[t];
                acc[5] += bhi(u[t].z) * w[t];
                acc[6] += blo(u[t].w) * w[t];
                acc[7] += bhi(u[t].w) * w[t];
            }
#pragma unroll
            for (int t = 0; t < 8; ++t) { s[t] = s2[t]; w[t] = w2[t]; }
        }

        uint4 o;
        o.x = pack2(fmaxf(acc[0] + bLo.x, 0.f), fmaxf(acc[1] + bLo.y, 0.f));
        o.y = pack2(fmaxf(acc[2] + bLo.z, 0.f), fmaxf(acc[3] + bLo.w, 0.f));
        o.z = pack2(fmaxf(acc[4] + bHi.x, 0.f), fmaxf(acc[5] + bHi.y, 0.f));
        o.w = pack2(fmaxf(acc[6] + bHi.z, 0.f), fmaxf(acc[7] + bHi.w, 0.f));
        *(uint4*)(hout + (long)node * JK_DIM + cl * 8) = o;
    }
}

// ---------------------------------------------------------------------------
// Final: out[n,40](f32) = hcat[n,192](bf16) @ Wlin[192,40] + blin.
// 64-row tile per 256-thread block; thread = 2 rows x 5 cols; Wt in LDS at
// pitch 196; pool reused as epilogue staging for coalesced float4 stores.
// ---------------------------------------------------------------------------
__global__ __launch_bounds__(256) void final_gemm(const unsigned short* __restrict__ hcat,
                                                  const float* __restrict__ Wt,
                                                  const float* __restrict__ b,
                                                  float* __restrict__ out, int n) {
    __shared__ float pool[OUT_DIM * W_PITCH];  // 31360 B
    int tid = threadIdx.x;
    for (int i = tid; i < OUT_DIM * 48; i += 256) {
        int c = i / 48;
        int q = (i - c * 48) * 4;
        *(float4*)(pool + c * W_PITCH + q) = *(const float4*)(Wt + (long)c * JK_DIM + q);
    }
    __syncthreads();

    int rg = tid >> 3;
    int cg = tid & 7;
    int c0 = cg * 5;
    int row0 = blockIdx.x * 64;
    int r0 = row0 + rg * 2;
    int ra = r0 < n ? r0 : n - 1;
    int rb = r0 + 1 < n ? r0 + 1 : n - 1;
    const unsigned short* ha = hcat + (long)ra * JK_DIM;
    const unsigned short* hb = hcat + (long)rb * JK_DIM;

    float acc[2][5];
#pragma unroll
    for (int r = 0; r < 2; ++r)
#pragma unroll
        for (int i = 0; i < 5; ++i) acc[r][i] = 0.f;

#pragma unroll 4
    for (int k = 0; k < JK_DIM; k += 4) {
        uint2 ua = *(const uint2*)(ha + k);
        uint2 ub = *(const uint2*)(hb + k);
        float4 va = make_float4(blo(ua.x), bhi(ua.x), blo(ua.y), bhi(ua.y));
        float4 vb = make_float4(blo(ub.x), bhi(ub.x), blo(ub.y), bhi(ub.y));
        float4 w0 = *(const float4*)(pool + (c0 + 0) * W_PITCH + k);
        float4 w1 = *(const float4*)(pool + (c0 + 1) * W_PITCH + k);
        float4 w2 = *(const float4*)(pool + (c0 + 2) * W_PITCH + k);
        float4 w3 = *(const float4*)(pool + (c0 + 3) * W_PITCH + k);
        float4 w4 = *(const float4*)(pool + (c0 + 4) * W_PITCH + k);
        acc[0][0] += va.x * w0.x + va.y * w0.y + va.z * w0.z + va.w * w0.w;
        acc[0][1] += va.x * w1.x + va.y * w1.y + va.z * w1.z + va.w * w1.w;
        acc[0][2] += va.x * w2.x + va.y * w2.y + va.z * w2.z + va.w * w2.w;
        acc[0][3] += va.x * w3.x + va.y * w3.y + va.z * w3.z + va.w * w3.w;
        acc[0][4] += va.x * w4.x + va.y * w4.y + va.z * w4.z + va.w * w4.w;
        acc[1][0] += vb.x * w0.x + vb.y * w0.y + vb.z * w0.z + vb.w * w0.w;
        acc[1][1] += vb.x * w1.x + vb.y * w1.y + vb.z * w1.z + vb.w * w1.w;
        acc[1][2] += vb.x * w2.x + vb.y * w2.y + vb.z * w2.z + vb.w * w2.w;
        acc[1][3] += vb.x * w3.x + vb.y * w3.y + vb.z * w3.z + vb.w * w3.w;
        acc[1][4] += vb.x * w4.x + vb.y * w4.y + vb.z * w4.z + vb.w * w4.w;
    }

    __syncthreads();
#pragma unroll
    for (int r = 0; r < 2; ++r)
#pragma unroll
        for (int i = 0; i < 5; ++i)
            pool[(rg * 2 + r) * FG_PITCH + c0 + i] = acc[r][i] + b[c0 + i];
    __syncthreads();

    if (row0 + 64 <= n) {
        for (int i = tid; i < 64 * OUT_DIM / 4; i += 256) {
            int f = i * 4;
            int row = f / OUT_DIM;
            int col = f - row * OUT_DIM;
            *(float4*)(out + (long)(row0 + row) * OUT_DIM + col) =
                *(const float4*)(pool + row * FG_PITCH + col);
        }
    } else {
        for (int i = tid; i < 64 * OUT_DIM; i += 256) {
            int row = i / OUT_DIM;
            int col = i - row * OUT_DIM;
            if (row0 + row < n)
                out[(long)(row0 + row) * OUT_DIM + col] = pool[row * FG_PITCH + col];
        }
    }
}

// ---------------------------------------------------------------------------
extern "C" void kernel_launch(void* const* d_in, const int* in_sizes, int n_in,
                              void* d_out, int out_size, void* d_ws, size_t ws_size,
                              hipStream_t stream) {
    const float* x    = (const float*)d_in[0];
    const int*   ei   = (const int*)d_in[1];
    const float* ew   = (const float*)d_in[2];
    const float* W1   = (const float*)d_in[3];
    const float* b1   = (const float*)d_in[4];
    const float* W2   = (const float*)d_in[5];
    const float* b2   = (const float*)d_in[6];
    const float* W3   = (const float*)d_in[7];
    const float* b3   = (const float*)d_in[8];
    const float* Wlin = (const float*)d_in[9];
    const float* blin = (const float*)d_in[10];
    float* out = (float*)d_out;

    const int N = in_sizes[0] / 128;   // 50000
    const int E = in_sizes[2];         // 800000
    const int* src = ei;
    const int* dst = ei + E;
    const int PART = (N + 7) / 8;      // 6250 nodes per XCD partition

    // Workspace: linb(bf16) | hcatb(bf16) | deg,off [N] | bsum | Wt | ecsr
    // rank[E] (ushort) ALIASES the hcatb region: rank is dead after
    // fill_and_gemm; hcatb is first written by the layer-1 aggregate, which
    // is stream-ordered after fill_and_gemm.
    char* wsb = (char*)d_ws;
    unsigned short* linb  = (unsigned short*)wsb;   wsb += (long)N * HID * 2;
    unsigned short* hcatb = (unsigned short*)wsb;   wsb += (long)N * JK_DIM * 2;
    int* deg    = (int*)wsb;                        wsb += (long)N * 4;
    int* off    = (int*)wsb;                        wsb += (long)N * 4;
    int* bsum   = (int*)wsb;                        wsb += 256 * 4;
    float* Wt   = (float*)wsb;                      wsb += (long)JK_DIM * OUT_DIM * 4;
    unsigned* ecsr = (unsigned*)wsb;
    unsigned short* rank = hcatb;  // aliased; lifetime ends before aggregate #1

    dim3 blk(256);
    const int nblkN = (N + 255) / 256;     // 196
    dim3 gN(nblkN);
    dim3 gHist(8 * 104);                   // 8 partitions x 104 blocks
    const int nGemm = (N + 63) / 64;       // 782 GEMM tiles (contiguous first)
    const int nFill = ((E >> 2) + 255) / 256;  // 782 fill blocks (contiguous after)
    dim3 gFG(nGemm + nFill);
    dim3 gGemm((N + 63) / 64);
    dim3 gAgg((N + 31) / 32);              // 8 nodes per wave
    dim3 gFin((N + 63) / 64);

    unsigned short* h1 = hcatb;            // columns [0,64)   of hcat[N,192]
    unsigned short* h2 = hcatb + HID;      // columns [64,128)
    unsigned short* h3 = hcatb + 2 * HID;  // columns [128,192)

    // ---- prep (zero deg + transpose Wlin), hist(+rank), scans ----
    prep<<<gN, blk, 0, stream>>>(deg, N, Wlin, Wt);
    hist_dst<<<gHist, blk, 0, stream>>>(dst, deg, rank, E, PART);
    scan_a<<<gN, blk, 0, stream>>>(deg, off, bsum, N);
    scan_b<<<1, blk, 0, stream>>>(bsum, nblkN);
    scan_c<<<gN, blk, 0, stream>>>(off, bsum, N);

    // ---- fused atomic-free CSR fill + layer-1 GEMM ----
    fill_and_gemm<<<gFG, blk, 0, stream>>>(src, dst, ew, off, rank, ecsr, E,
                                           x, W1, linb, N, nGemm);
    aggregate<<<gAgg, blk, 0, stream>>>(linb, ecsr, off, deg, b1, h1, N);

    // ---- layer 2 (K=64, bf16 input from hcat col block) ----
    gemm_b16in<<<gGemm, blk, 0, stream>>>(h1, W2, linb, N);
    aggregate<<<gAgg, blk, 0, stream>>>(linb, ecsr, off, deg, b2, h2, N);

    // ---- layer 3 ----
    gemm_b16in<<<gGemm, blk, 0, stream>>>(h2, W3, linb, N);
    aggregate<<<gAgg, blk, 0, stream>>>(linb, ecsr, off, deg, b3, h3, N);

    // ---- JK linear ----
    final_gemm<<<gFin, blk, 0, stream>>>(hcatb, Wt, blin, out, N);
}

// Round 4
// 259.976 us; speedup vs baseline: 1.1467x; 1.0850x over previous
//
#include <hip/hip_runtime.h>

// Problem constants: N=50000, E=800000, IN=128, HID=64, OUT=40
#define HID 64
#define JK_DIM 192
#define OUT_DIM 40
#define AP 136         // bf16 LDS pitch for 128-wide tiles (272B: 16B-aligned, 4-bank row shift)
#define HP 72          // bf16 LDS pitch for 64-wide tiles (144B: 16B-aligned, 4-bank row shift)
#define W_PITCH 196    // final_gemm LDS pitch for Wt rows
#define FG_PITCH 44    // final_gemm epilogue staging pitch

typedef __attribute__((ext_vector_type(8))) short bf16x8;
typedef __attribute__((ext_vector_type(4))) float f32x4;

// bf16 helpers (RNE pack; packed-word unpack via shift/mask)
__device__ inline unsigned short f2b(float f) {
    unsigned u = __float_as_uint(f);
    unsigned r = u + 0x7FFF + ((u >> 16) & 1);
    return (unsigned short)(r >> 16);
}
__device__ inline float b2f(unsigned short u) {
    return __uint_as_float(((unsigned)u) << 16);
}
__device__ inline float blo(unsigned u) { return __uint_as_float(u << 16); }
__device__ inline float bhi(unsigned u) { return __uint_as_float(u & 0xFFFF0000u); }
__device__ inline unsigned pack2(float a, float b) {
    return (unsigned)f2b(a) | ((unsigned)f2b(b) << 16);
}

// ---------------------------------------------------------------------------
// prep: zero deg + gctr + transpose Wlin[192,40] -> Wt[40,192].
// ---------------------------------------------------------------------------
__global__ __launch_bounds__(256) void prep(int* __restrict__ deg, int n,
                                            const float* __restrict__ W,
                                            float* __restrict__ Wt,
                                            int* __restrict__ gctr) {
    int i = blockIdx.x * 256 + threadIdx.x;
    if (i == 0) gctr[0] = 0;
    if (i < n) deg[i] = 0;
    if (i < JK_DIM * OUT_DIM) {
        int k = i / OUT_DIM;
        int c = i - k * OUT_DIM;
        Wt[c * JK_DIM + k] = W[i];
    }
}

// ---------------------------------------------------------------------------
// XCD-partitioned histogram. Records each edge's arrival rank so the CSR
// fill needs no atomics.
// ---------------------------------------------------------------------------
__global__ __launch_bounds__(256) void hist_dst(const int* __restrict__ dst,
                                                int* __restrict__ deg,
                                                unsigned short* __restrict__ rank,
                                                int E, int part) {
    int p = blockIdx.x & 7;
    int bid = blockIdx.x >> 3;
    int nblk = gridDim.x >> 3;
    int lo = p * part, hi = lo + part;
    int E4 = E >> 2;
    for (int q = bid * 256 + threadIdx.x; q < E4; q += nblk * 256) {
        int4 d4 = ((const int4*)dst)[q];
        int e = q * 4;
        if (d4.x >= lo && d4.x < hi) rank[e + 0] = (unsigned short)atomicAdd(&deg[d4.x], 1);
        if (d4.y >= lo && d4.y < hi) rank[e + 1] = (unsigned short)atomicAdd(&deg[d4.y], 1);
        if (d4.z >= lo && d4.z < hi) rank[e + 2] = (unsigned short)atomicAdd(&deg[d4.z], 1);
        if (d4.w >= lo && d4.w < hi) rank[e + 3] = (unsigned short)atomicAdd(&deg[d4.w], 1);
    }
    if (bid == 0 && threadIdx.x < (E & 3)) {
        int e = (E & ~3) + threadIdx.x;
        int d = dst[e];
        if (d >= lo && d < hi) rank[e] = (unsigned short)atomicAdd(&deg[d], 1);
    }
}

// ---------------------------------------------------------------------------
// Single-pass scan: block-local prefix + one atomicAdd per block for the
// base. Block bases land in arbitrary order -> off[] is non-monotonic across
// blocks, which is fine: CSR only needs disjoint per-node slot ranges.
// ---------------------------------------------------------------------------
__global__ __launch_bounds__(256) void scan_fused(const int* __restrict__ deg,
                                                  int* __restrict__ off,
                                                  int* __restrict__ gctr, int n) {
    __shared__ int tmp[256];
    __shared__ int base;
    int i = blockIdx.x * 256 + threadIdx.x;
    int v = (i < n) ? deg[i] : 0;
    tmp[threadIdx.x] = v;
    __syncthreads();
    for (int d = 1; d < 256; d <<= 1) {
        int t = (threadIdx.x >= d) ? tmp[threadIdx.x - d] : 0;
        __syncthreads();
        tmp[threadIdx.x] += t;
        __syncthreads();
    }
    if (threadIdx.x == 255) base = atomicAdd(gctr, tmp[255]);
    __syncthreads();
    if (i < n) off[i] = base + tmp[threadIdx.x] - v;
}

// ---------------------------------------------------------------------------
// FUSED: atomic-free CSR fill + layer-1 GEMM (MFMA bf16).
// Blocks [0, nFill)   -> fill: one int4 edge-group/thread, slot=off[dst]+rank.
//                        Fill first: short blocks churn fast, GEMM backfills.
// Blocks [nFill, ...) -> one 64-row GEMM tile: lin1 = x[64x128] @ W1[128x64]
//                        via v_mfma_f32_16x16x32_bf16, A and Wt staged bf16.
// ---------------------------------------------------------------------------
__global__ __launch_bounds__(256) void fill_and_gemm(
        const int* __restrict__ src, const int* __restrict__ dst,
        const float* __restrict__ ew, const int* __restrict__ off,
        const unsigned short* __restrict__ rank,
        unsigned* __restrict__ ecsr, int E,
        const float* __restrict__ x, const float* __restrict__ W1,
        unsigned short* __restrict__ linb, int n, int nFill) {
    __shared__ unsigned short Ah[64 * AP];   // A tile, bf16
    __shared__ unsigned short Wt[64 * AP];   // W1^T tile, bf16: Wt[n][k]=W1[k][n]
    int tid = threadIdx.x;
    if ((int)blockIdx.x < nFill) {
        // ---- fill branch: no atomics, one int4 per thread ----
        int q = blockIdx.x * 256 + tid;
        int E4 = E >> 2;
        if (q < E4) {
            int4 d4 = ((const int4*)dst)[q];
            int4 s4 = ((const int4*)src)[q];
            float4 wv = ((const float4*)ew)[q];
            ushort4 r4 = ((const ushort4*)rank)[q];
            ecsr[off[d4.x] + r4.x] = (unsigned)s4.x | ((unsigned)f2b(wv.x) << 16);
            ecsr[off[d4.y] + r4.y] = (unsigned)s4.y | ((unsigned)f2b(wv.y) << 16);
            ecsr[off[d4.z] + r4.z] = (unsigned)s4.z | ((unsigned)f2b(wv.z) << 16);
            ecsr[off[d4.w] + r4.w] = (unsigned)s4.w | ((unsigned)f2b(wv.w) << 16);
        }
        if (blockIdx.x == 0 && tid < (E & 3)) {
            int e = (E & ~3) + tid;
            int d = dst[e];
            ecsr[off[d] + rank[e]] = (unsigned)src[e] | ((unsigned)f2b(ew[e]) << 16);
        }
        return;
    }
    // ---- gemm branch ----
    int row0 = (blockIdx.x - nFill) * 64;
    if (row0 >= n) return;
    // stage A: x[row0..row0+63][0..127] f32 -> bf16
    for (int i = tid; i < 64 * 32; i += 256) {
        int r = i >> 5;
        int c4 = (i & 31) * 4;
        int grow = row0 + r;
        if (grow >= n) grow = n - 1;
        float4 v = *(const float4*)(x + (long)grow * 128 + c4);
        ushort4 o;
        o.x = f2b(v.x); o.y = f2b(v.y); o.z = f2b(v.z); o.w = f2b(v.w);
        *(ushort4*)(Ah + r * AP + c4) = o;
    }
    // stage Wt (transposed, bf16): Wt[n][k] = W1[k][n]
    for (int i = tid; i < 128 * 16; i += 256) {
        int k = i >> 4;
        int n4 = (i & 15) * 4;
        float4 v = *(const float4*)(W1 + (long)k * 64 + n4);
        Wt[(n4 + 0) * AP + k] = f2b(v.x);
        Wt[(n4 + 1) * AP + k] = f2b(v.y);
        Wt[(n4 + 2) * AP + k] = f2b(v.z);
        Wt[(n4 + 3) * AP + k] = f2b(v.w);
    }
    __syncthreads();

    int wave = tid >> 6;
    int lane = tid & 63;
    int lr = lane & 15;            // A row / B col / D col
    int lk = (lane >> 4) * 8;      // k offset within 32-chunk
    f32x4 acc[4];
#pragma unroll
    for (int nf = 0; nf < 4; ++nf) acc[nf] = (f32x4){0.f, 0.f, 0.f, 0.f};
#pragma unroll
    for (int k0 = 0; k0 < 128; k0 += 32) {
        bf16x8 a = *(const bf16x8*)(Ah + (wave * 16 + lr) * AP + k0 + lk);
#pragma unroll
        for (int nf = 0; nf < 4; ++nf) {
            bf16x8 b = *(const bf16x8*)(Wt + (nf * 16 + lr) * AP + k0 + lk);
            acc[nf] = __builtin_amdgcn_mfma_f32_16x16x32_bf16(a, b, acc[nf], 0, 0, 0);
        }
    }
    // epilogue: D[m][nf*16+lr], m = wave*16 + (lane>>4)*4 + reg
    int mbase = wave * 16 + (lane >> 4) * 4;
#pragma unroll
    for (int nf = 0; nf < 4; ++nf) {
#pragma unroll
        for (int r = 0; r < 4; ++r) {
            int grow = row0 + mbase + r;
            if (grow < n)
                linb[(long)grow * HID + nf * 16 + lr] = f2b(acc[nf][r]);
        }
    }
}

// ---------------------------------------------------------------------------
// Layers 2/3 GEMM via MFMA: lin = h[64x64](bf16, row stride JK_DIM) @ W[64x64].
// ---------------------------------------------------------------------------
__global__ __launch_bounds__(256) void gemm_b16in(const unsigned short* __restrict__ h,
                                                  const float* __restrict__ W,
                                                  unsigned short* __restrict__ outb,
                                                  int n) {
    __shared__ unsigned short Hs[64 * HP];
    __shared__ unsigned short Wt[64 * HP];   // Wt[n][k] = W[k][n], bf16
    int tid = threadIdx.x;
    int row0 = blockIdx.x * 64;
    if (row0 >= n) return;
    for (int i = tid; i < 64 * 8; i += 256) {
        int r = i >> 3;
        int q = (i & 7) * 8;
        int grow = row0 + r;
        if (grow >= n) grow = n - 1;
        uint4 u = *(const uint4*)(h + (long)grow * JK_DIM + q);
        *(uint4*)(Hs + r * HP + q) = u;
    }
    for (int i = tid; i < 64 * 16; i += 256) {
        int k = i >> 4;
        int n4 = (i & 15) * 4;
        float4 v = *(const float4*)(W + (long)k * 64 + n4);
        Wt[(n4 + 0) * HP + k] = f2b(v.x);
        Wt[(n4 + 1) * HP + k] = f2b(v.y);
        Wt[(n4 + 2) * HP + k] = f2b(v.z);
        Wt[(n4 + 3) * HP + k] = f2b(v.w);
    }
    __syncthreads();

    int wave = tid >> 6;
    int lane = tid & 63;
    int lr = lane & 15;
    int lk = (lane >> 4) * 8;
    f32x4 acc[4];
#pragma unroll
    for (int nf = 0; nf < 4; ++nf) acc[nf] = (f32x4){0.f, 0.f, 0.f, 0.f};
#pragma unroll
    for (int k0 = 0; k0 < 64; k0 += 32) {
        bf16x8 a = *(const bf16x8*)(Hs + (wave * 16 + lr) * HP + k0 + lk);
#pragma unroll
        for (int nf = 0; nf < 4; ++nf) {
            bf16x8 b = *(const bf16x8*)(Wt + (nf * 16 + lr) * HP + k0 + lk);
            acc[nf] = __builtin_amdgcn_mfma_f32_16x16x32_bf16(a, b, acc[nf], 0, 0, 0);
        }
    }
    int mbase = wave * 16 + (lane >> 4) * 4;
#pragma unroll
    for (int nf = 0; nf < 4; ++nf) {
#pragma unroll
        for (int r = 0; r < 4; ++r) {
            int grow = row0 + mbase + r;
            if (grow < n)
                outb[(long)grow * HID + nf * 16 + lr] = f2b(acc[nf][r]);
        }
    }
}

// ---------------------------------------------------------------------------
// Aggregate + bias + ReLU. One 8-lane group per node (8 nodes/wave); lane
// covers 16B (8 bf16 cols). 8-stream software pipeline.
// ---------------------------------------------------------------------------
__global__ __launch_bounds__(256) void aggregate(const unsigned short* __restrict__ linb,
                                                 const unsigned* __restrict__ ecsr,
                                                 const int* __restrict__ off,
                                                 const int* __restrict__ deg,
                                                 const float* __restrict__ bias,
                                                 unsigned short* __restrict__ hout, int n) {
    int cl = threadIdx.x & 7;       // 16B slice within the 128B bf16 row
    float4 bLo = *(const float4*)(bias + cl * 8);
    float4 bHi = *(const float4*)(bias + cl * 8 + 4);
    int grp = (blockIdx.x * 256 + threadIdx.x) >> 3;
    int ngrp = (gridDim.x * 256) >> 3;
    for (int node = grp; node < n; node += ngrp) {
        int start = off[node];
        int cnt = deg[node];
        float acc[8];
#pragma unroll
        for (int i = 0; i < 8; ++i) acc[i] = 0.f;

        int s[8];
        float w[8];
#pragma unroll
        for (int t = 0; t < 8; ++t) {
            s[t] = 0; w[t] = 0.f;
            if (t < cnt) {
                unsigned m = ecsr[start + t];
                s[t] = (int)(m & 0xFFFFu);
                w[t] = b2f((unsigned short)(m >> 16));
            }
        }
        for (int bb = 0; bb < cnt; bb += 8) {
            int s2[8];
            float w2[8];
#pragma unroll
            for (int t = 0; t < 8; ++t) {
                int e = bb + 8 + t;
                s2[t] = 0; w2[t] = 0.f;
                if (e < cnt) {
                    unsigned m = ecsr[start + e];
                    s2[t] = (int)(m & 0xFFFFu);
                    w2[t] = b2f((unsigned short)(m >> 16));
                }
            }
            uint4 u[8];
#pragma unroll
            for (int t = 0; t < 8; ++t)
                u[t] = *(const uint4*)(linb + (long)s[t] * HID + cl * 8);
#pragma unroll
            for (int t = 0; t < 8; ++t) {
                acc[0] += blo(u[t].x) * w[t];
                acc[1] += bhi(u[t].x) * w[t];
                acc[2] += blo(u[t].y) * w[t];
                acc[3] += bhi(u[t].y) * w[t];
                acc[4] += blo(u[t].z) * w[t];
                acc[5] += bhi(u[t].z) * w[t];
                acc[6] += blo(u[t].w) * w[t];
                acc[7] += bhi(u[t].w) * w[t];
            }
#pragma unroll
            for (int t = 0; t < 8; ++t) { s[t] = s2[t]; w[t] = w2[t]; }
        }

        uint4 o;
        o.x = pack2(fmaxf(acc[0] + bLo.x, 0.f), fmaxf(acc[1] + bLo.y, 0.f));
        o.y = pack2(fmaxf(acc[2] + bLo.z, 0.f), fmaxf(acc[3] + bLo.w, 0.f));
        o.z = pack2(fmaxf(acc[4] + bHi.x, 0.f), fmaxf(acc[5] + bHi.y, 0.f));
        o.w = pack2(fmaxf(acc[6] + bHi.z, 0.f), fmaxf(acc[7] + bHi.w, 0.f));
        *(uint4*)(hout + (long)node * JK_DIM + cl * 8) = o;
    }
}

// ---------------------------------------------------------------------------
// Final: out[n,40](f32) = hcat[n,192](bf16) @ Wlin[192,40] + blin.
// ---------------------------------------------------------------------------
__global__ __launch_bounds__(256) void final_gemm(const unsigned short* __restrict__ hcat,
                                                  const float* __restrict__ Wt,
                                                  const float* __restrict__ b,
                                                  float* __restrict__ out, int n) {
    __shared__ float pool[OUT_DIM * W_PITCH];  // 31360 B
    int tid = threadIdx.x;
    for (int i = tid; i < OUT_DIM * 48; i += 256) {
        int c = i / 48;
        int q = (i - c * 48) * 4;
        *(float4*)(pool + c * W_PITCH + q) = *(const float4*)(Wt + (long)c * JK_DIM + q);
    }
    __syncthreads();

    int rg = tid >> 3;
    int cg = tid & 7;
    int c0 = cg * 5;
    int row0 = blockIdx.x * 64;
    int r0 = row0 + rg * 2;
    int ra = r0 < n ? r0 : n - 1;
    int rb = r0 + 1 < n ? r0 + 1 : n - 1;
    const unsigned short* ha = hcat + (long)ra * JK_DIM;
    const unsigned short* hb = hcat + (long)rb * JK_DIM;

    float acc[2][5];
#pragma unroll
    for (int r = 0; r < 2; ++r)
#pragma unroll
        for (int i = 0; i < 5; ++i) acc[r][i] = 0.f;

#pragma unroll 4
    for (int k = 0; k < JK_DIM; k += 4) {
        uint2 ua = *(const uint2*)(ha + k);
        uint2 ub = *(const uint2*)(hb + k);
        float4 va = make_float4(blo(ua.x), bhi(ua.x), blo(ua.y), bhi(ua.y));
        float4 vb = make_float4(blo(ub.x), bhi(ub.x), blo(ub.y), bhi(ub.y));
        float4 w0 = *(const float4*)(pool + (c0 + 0) * W_PITCH + k);
        float4 w1 = *(const float4*)(pool + (c0 + 1) * W_PITCH + k);
        float4 w2 = *(const float4*)(pool + (c0 + 2) * W_PITCH + k);
        float4 w3 = *(const float4*)(pool + (c0 + 3) * W_PITCH + k);
        float4 w4 = *(const float4*)(pool + (c0 + 4) * W_PITCH + k);
        acc[0][0] += va.x * w0.x + va.y * w0.y + va.z * w0.z + va.w * w0.w;
        acc[0][1] += va.x * w1.x + va.y * w1.y + va.z * w1.z + va.w * w1.w;
        acc[0][2] += va.x * w2.x + va.y * w2.y + va.z * w2.z + va.w * w2.w;
        acc[0][3] += va.x * w3.x + va.y * w3.y + va.z * w3.z + va.w * w3.w;
        acc[0][4] += va.x * w4.x + va.y * w4.y + va.z * w4.z + va.w * w4.w;
        acc[1][0] += vb.x * w0.x + vb.y * w0.y + vb.z * w0.z + vb.w * w0.w;
        acc[1][1] += vb.x * w1.x + vb.y * w1.y + vb.z * w1.z + vb.w * w1.w;
        acc[1][2] += vb.x * w2.x + vb.y * w2.y + vb.z * w2.z + vb.w * w2.w;
        acc[1][3] += vb.x * w3.x + vb.y * w3.y + vb.z * w3.z + vb.w * w3.w;
        acc[1][4] += vb.x * w4.x + vb.y * w4.y + vb.z * w4.z + vb.w * w4.w;
    }

    __syncthreads();
#pragma unroll
    for (int r = 0; r < 2; ++r)
#pragma unroll
        for (int i = 0; i < 5; ++i)
            pool[(rg * 2 + r) * FG_PITCH + c0 + i] = acc[r][i] + b[c0 + i];
    __syncthreads();

    if (row0 + 64 <= n) {
        for (int i = tid; i < 64 * OUT_DIM / 4; i += 256) {
            int f = i * 4;
            int row = f / OUT_DIM;
            int col = f - row * OUT_DIM;
            *(float4*)(out + (long)(row0 + row) * OUT_DIM + col) =
                *(const float4*)(pool + row * FG_PITCH + col);
        }
    } else {
        for (int i = tid; i < 64 * OUT_DIM; i += 256) {
            int row = i / OUT_DIM;
            int col = i - row * OUT_DIM;
            if (row0 + row < n)
                out[(long)(row0 + row) * OUT_DIM + col] = pool[row * FG_PITCH + col];
        }
    }
}

// ---------------------------------------------------------------------------
extern "C" void kernel_launch(void* const* d_in, const int* in_sizes, int n_in,
                              void* d_out, int out_size, void* d_ws, size_t ws_size,
                              hipStream_t stream) {
    const float* x    = (const float*)d_in[0];
    const int*   ei   = (const int*)d_in[1];
    const float* ew   = (const float*)d_in[2];
    const float* W1   = (const float*)d_in[3];
    const float* b1   = (const float*)d_in[4];
    const float* W2   = (const float*)d_in[5];
    const float* b2   = (const float*)d_in[6];
    const float* W3   = (const float*)d_in[7];
    const float* b3   = (const float*)d_in[8];
    const float* Wlin = (const float*)d_in[9];
    const float* blin = (const float*)d_in[10];
    float* out = (float*)d_out;

    const int N = in_sizes[0] / 128;   // 50000
    const int E = in_sizes[2];         // 800000
    const int* src = ei;
    const int* dst = ei + E;
    const int PART = (N + 7) / 8;      // 6250 nodes per XCD partition

    // Workspace: linb(bf16) | hcatb(bf16) | deg,off [N] | bsum | Wt | ecsr
    // rank[E] (ushort) ALIASES hcatb: rank dies before aggregate #1 writes hcatb.
    char* wsb = (char*)d_ws;
    unsigned short* linb  = (unsigned short*)wsb;   wsb += (long)N * HID * 2;
    unsigned short* hcatb = (unsigned short*)wsb;   wsb += (long)N * JK_DIM * 2;
    int* deg    = (int*)wsb;                        wsb += (long)N * 4;
    int* off    = (int*)wsb;                        wsb += (long)N * 4;
    int* bsum   = (int*)wsb;                        wsb += 256 * 4;
    float* Wt   = (float*)wsb;                      wsb += (long)JK_DIM * OUT_DIM * 4;
    unsigned* ecsr = (unsigned*)wsb;
    unsigned short* rank = hcatb;      // aliased
    int* gctr = bsum;                  // scan global counter (bsum slot reused)

    dim3 blk(256);
    const int nblkN = (N + 255) / 256;     // 196
    dim3 gN(nblkN);
    dim3 gHist(8 * 104);                   // 8 partitions x 104 blocks
    const int nFill = ((E >> 2) + 255) / 256;  // 782 fill blocks (first)
    const int nGemm = (N + 63) / 64;           // 782 GEMM tiles (after)
    dim3 gFG(nFill + nGemm);
    dim3 gGemm((N + 63) / 64);
    dim3 gAgg((N + 31) / 32);              // 8 nodes per wave
    dim3 gFin((N + 63) / 64);

    unsigned short* h1 = hcatb;            // columns [0,64)   of hcat[N,192]
    unsigned short* h2 = hcatb + HID;      // columns [64,128)
    unsigned short* h3 = hcatb + 2 * HID;  // columns [128,192)

    // ---- prep (zero deg+gctr, transpose Wlin), hist(+rank), fused scan ----
    prep<<<gN, blk, 0, stream>>>(deg, N, Wlin, Wt, gctr);
    hist_dst<<<gHist, blk, 0, stream>>>(dst, deg, rank, E, PART);
    scan_fused<<<gN, blk, 0, stream>>>(deg, off, gctr, N);

    // ---- fused atomic-free CSR fill + layer-1 MFMA GEMM ----
    fill_and_gemm<<<gFG, blk, 0, stream>>>(src, dst, ew, off, rank, ecsr, E,
                                           x, W1, linb, N, nFill);
    aggregate<<<gAgg, blk, 0, stream>>>(linb, ecsr, off, deg, b1, h1, N);

    // ---- layer 2 (K=64, bf16 input from hcat col block) ----
    gemm_b16in<<<gGemm, blk, 0, stream>>>(h1, W2, linb, N);
    aggregate<<<gAgg, blk, 0, stream>>>(linb, ecsr, off, deg, b2, h2, N);

    // ---- layer 3 ----
    gemm_b16in<<<gGemm, blk, 0, stream>>>(h2, W3, linb, N);
    aggregate<<<gAgg, blk, 0, stream>>>(linb, ecsr, off, deg, b3, h3, N);

    // ---- JK linear ----
    final_gemm<<<gFin, blk, 0, stream>>>(hcatb, Wt, blin, out, N);
}

// Round 5
// 257.527 us; speedup vs baseline: 1.1576x; 1.0095x over previous
//
#include <hip/hip_runtime.h>

// Problem constants: N=50000, E=800000, IN=128, HID=64, OUT=40
#define HID 64
#define JK_DIM 192
#define OUT_DIM 40
#define AP 136         // bf16 LDS pitch for 128-wide tiles
#define HP 72          // bf16 LDS pitch for 64-wide tiles (144B: 16B-aligned, 2-way max)
#define W_PITCH 196    // final_gemm LDS pitch for Wt rows
#define FG_PITCH 44    // final_gemm epilogue staging pitch

typedef __attribute__((ext_vector_type(8))) short bf16x8;
typedef __attribute__((ext_vector_type(4))) float f32x4;

// bf16 helpers (RNE pack; packed-word unpack via shift/mask)
__device__ inline unsigned short f2b(float f) {
    unsigned u = __float_as_uint(f);
    unsigned r = u + 0x7FFF + ((u >> 16) & 1);
    return (unsigned short)(r >> 16);
}
__device__ inline float b2f(unsigned short u) {
    return __uint_as_float(((unsigned)u) << 16);
}
__device__ inline float blo(unsigned u) { return __uint_as_float(u << 16); }
__device__ inline float bhi(unsigned u) { return __uint_as_float(u & 0xFFFF0000u); }
__device__ inline unsigned pack2(float a, float b) {
    return (unsigned)f2b(a) | ((unsigned)f2b(b) << 16);
}

// ---------------------------------------------------------------------------
// prep: zero deg + gctr + transpose Wlin[192,40] -> Wt[40,192].
// ---------------------------------------------------------------------------
__global__ __launch_bounds__(256) void prep(int* __restrict__ deg, int n,
                                            const float* __restrict__ W,
                                            float* __restrict__ Wt,
                                            int* __restrict__ gctr) {
    int i = blockIdx.x * 256 + threadIdx.x;
    if (i == 0) gctr[0] = 0;
    if (i < n) deg[i] = 0;
    if (i < JK_DIM * OUT_DIM) {
        int k = i / OUT_DIM;
        int c = i - k * OUT_DIM;
        Wt[c * JK_DIM + k] = W[i];
    }
}

// ---------------------------------------------------------------------------
// XCD-partitioned histogram. Records each edge's arrival rank so the CSR
// fill needs no atomics.
// ---------------------------------------------------------------------------
__global__ __launch_bounds__(256) void hist_dst(const int* __restrict__ dst,
                                                int* __restrict__ deg,
                                                unsigned short* __restrict__ rank,
                                                int E, int part) {
    int p = blockIdx.x & 7;
    int bid = blockIdx.x >> 3;
    int nblk = gridDim.x >> 3;
    int lo = p * part, hi = lo + part;
    int E4 = E >> 2;
    for (int q = bid * 256 + threadIdx.x; q < E4; q += nblk * 256) {
        int4 d4 = ((const int4*)dst)[q];
        int e = q * 4;
        if (d4.x >= lo && d4.x < hi) rank[e + 0] = (unsigned short)atomicAdd(&deg[d4.x], 1);
        if (d4.y >= lo && d4.y < hi) rank[e + 1] = (unsigned short)atomicAdd(&deg[d4.y], 1);
        if (d4.z >= lo && d4.z < hi) rank[e + 2] = (unsigned short)atomicAdd(&deg[d4.z], 1);
        if (d4.w >= lo && d4.w < hi) rank[e + 3] = (unsigned short)atomicAdd(&deg[d4.w], 1);
    }
    if (bid == 0 && threadIdx.x < (E & 3)) {
        int e = (E & ~3) + threadIdx.x;
        int d = dst[e];
        if (d >= lo && d < hi) rank[e] = (unsigned short)atomicAdd(&deg[d], 1);
    }
}

// ---------------------------------------------------------------------------
// Single-pass scan: block-local prefix + one atomicAdd per block for the
// base. off[] is non-monotonic across blocks; CSR only needs disjoint ranges.
// ---------------------------------------------------------------------------
__global__ __launch_bounds__(256) void scan_fused(const int* __restrict__ deg,
                                                  int* __restrict__ off,
                                                  int* __restrict__ gctr, int n) {
    __shared__ int tmp[256];
    __shared__ int base;
    int i = blockIdx.x * 256 + threadIdx.x;
    int v = (i < n) ? deg[i] : 0;
    tmp[threadIdx.x] = v;
    __syncthreads();
    for (int d = 1; d < 256; d <<= 1) {
        int t = (threadIdx.x >= d) ? tmp[threadIdx.x - d] : 0;
        __syncthreads();
        tmp[threadIdx.x] += t;
        __syncthreads();
    }
    if (threadIdx.x == 255) base = atomicAdd(gctr, tmp[255]);
    __syncthreads();
    if (i < n) off[i] = base + tmp[threadIdx.x] - v;
}

// ---------------------------------------------------------------------------
// FUSED: atomic-free CSR fill + layer-1 GEMM (MFMA bf16).
// ---------------------------------------------------------------------------
__global__ __launch_bounds__(256) void fill_and_gemm(
        const int* __restrict__ src, const int* __restrict__ dst,
        const float* __restrict__ ew, const int* __restrict__ off,
        const unsigned short* __restrict__ rank,
        unsigned* __restrict__ ecsr, int E,
        const float* __restrict__ x, const float* __restrict__ W1,
        unsigned short* __restrict__ linb, int n, int nFill) {
    __shared__ unsigned short Ah[64 * AP];   // A tile, bf16
    __shared__ unsigned short Wt[64 * AP];   // W1^T tile, bf16: Wt[n][k]=W1[k][n]
    int tid = threadIdx.x;
    if ((int)blockIdx.x < nFill) {
        // ---- fill branch: no atomics, one int4 per thread ----
        int q = blockIdx.x * 256 + tid;
        int E4 = E >> 2;
        if (q < E4) {
            int4 d4 = ((const int4*)dst)[q];
            int4 s4 = ((const int4*)src)[q];
            float4 wv = ((const float4*)ew)[q];
            ushort4 r4 = ((const ushort4*)rank)[q];
            ecsr[off[d4.x] + r4.x] = (unsigned)s4.x | ((unsigned)f2b(wv.x) << 16);
            ecsr[off[d4.y] + r4.y] = (unsigned)s4.y | ((unsigned)f2b(wv.y) << 16);
            ecsr[off[d4.z] + r4.z] = (unsigned)s4.z | ((unsigned)f2b(wv.z) << 16);
            ecsr[off[d4.w] + r4.w] = (unsigned)s4.w | ((unsigned)f2b(wv.w) << 16);
        }
        if (blockIdx.x == 0 && tid < (E & 3)) {
            int e = (E & ~3) + tid;
            int d = dst[e];
            ecsr[off[d] + rank[e]] = (unsigned)src[e] | ((unsigned)f2b(ew[e]) << 16);
        }
        return;
    }
    // ---- gemm branch: lin1 = x[64x128] @ W1[128x64] via MFMA ----
    int row0 = (blockIdx.x - nFill) * 64;
    if (row0 >= n) return;
    for (int i = tid; i < 64 * 32; i += 256) {
        int r = i >> 5;
        int c4 = (i & 31) * 4;
        int grow = row0 + r;
        if (grow >= n) grow = n - 1;
        float4 v = *(const float4*)(x + (long)grow * 128 + c4);
        ushort4 o;
        o.x = f2b(v.x); o.y = f2b(v.y); o.z = f2b(v.z); o.w = f2b(v.w);
        *(ushort4*)(Ah + r * AP + c4) = o;
    }
    for (int i = tid; i < 128 * 16; i += 256) {
        int k = i >> 4;
        int n4 = (i & 15) * 4;
        float4 v = *(const float4*)(W1 + (long)k * 64 + n4);
        Wt[(n4 + 0) * AP + k] = f2b(v.x);
        Wt[(n4 + 1) * AP + k] = f2b(v.y);
        Wt[(n4 + 2) * AP + k] = f2b(v.z);
        Wt[(n4 + 3) * AP + k] = f2b(v.w);
    }
    __syncthreads();

    int wave = tid >> 6;
    int lane = tid & 63;
    int lr = lane & 15;
    int lk = (lane >> 4) * 8;
    f32x4 acc[4];
#pragma unroll
    for (int nf = 0; nf < 4; ++nf) acc[nf] = (f32x4){0.f, 0.f, 0.f, 0.f};
#pragma unroll
    for (int k0 = 0; k0 < 128; k0 += 32) {
        bf16x8 a = *(const bf16x8*)(Ah + (wave * 16 + lr) * AP + k0 + lk);
#pragma unroll
        for (int nf = 0; nf < 4; ++nf) {
            bf16x8 b = *(const bf16x8*)(Wt + (nf * 16 + lr) * AP + k0 + lk);
            acc[nf] = __builtin_amdgcn_mfma_f32_16x16x32_bf16(a, b, acc[nf], 0, 0, 0);
        }
    }
    int mbase = wave * 16 + (lane >> 4) * 4;
#pragma unroll
    for (int nf = 0; nf < 4; ++nf) {
#pragma unroll
        for (int r = 0; r < 4; ++r) {
            int grow = row0 + mbase + r;
            if (grow < n)
                linb[(long)grow * HID + nf * 16 + lr] = f2b(acc[nf][r]);
        }
    }
}

// ---------------------------------------------------------------------------
// Aggregate + bias + ReLU (layer 1). 8-lane group per node; 8-deep pipeline.
// ---------------------------------------------------------------------------
__global__ __launch_bounds__(256) void aggregate(const unsigned short* __restrict__ linb,
                                                 const unsigned* __restrict__ ecsr,
                                                 const int* __restrict__ off,
                                                 const int* __restrict__ deg,
                                                 const float* __restrict__ bias,
                                                 unsigned short* __restrict__ hout, int n) {
    int cl = threadIdx.x & 7;
    float4 bLo = *(const float4*)(bias + cl * 8);
    float4 bHi = *(const float4*)(bias + cl * 8 + 4);
    int grp = (blockIdx.x * 256 + threadIdx.x) >> 3;
    int ngrp = (gridDim.x * 256) >> 3;
    for (int node = grp; node < n; node += ngrp) {
        int start = off[node];
        int cnt = deg[node];
        float acc[8];
#pragma unroll
        for (int i = 0; i < 8; ++i) acc[i] = 0.f;

        int s[8];
        float w[8];
#pragma unroll
        for (int t = 0; t < 8; ++t) {
            s[t] = 0; w[t] = 0.f;
            if (t < cnt) {
                unsigned m = ecsr[start + t];
                s[t] = (int)(m & 0xFFFFu);
                w[t] = b2f((unsigned short)(m >> 16));
            }
        }
        for (int bb = 0; bb < cnt; bb += 8) {
            int s2[8];
            float w2[8];
#pragma unroll
            for (int t = 0; t < 8; ++t) {
                int e = bb + 8 + t;
                s2[t] = 0; w2[t] = 0.f;
                if (e < cnt) {
                    unsigned m = ecsr[start + e];
                    s2[t] = (int)(m & 0xFFFFu);
                    w2[t] = b2f((unsigned short)(m >> 16));
                }
            }
            uint4 u[8];
#pragma unroll
            for (int t = 0; t < 8; ++t)
                u[t] = *(const uint4*)(linb + (long)s[t] * HID + cl * 8);
#pragma unroll
            for (int t = 0; t < 8; ++t) {
                acc[0] += blo(u[t].x) * w[t];
                acc[1] += bhi(u[t].x) * w[t];
                acc[2] += blo(u[t].y) * w[t];
                acc[3] += bhi(u[t].y) * w[t];
                acc[4] += blo(u[t].z) * w[t];
                acc[5] += bhi(u[t].z) * w[t];
                acc[6] += blo(u[t].w) * w[t];
                acc[7] += bhi(u[t].w) * w[t];
            }
#pragma unroll
            for (int t = 0; t < 8; ++t) { s[t] = s2[t]; w[t] = w2[t]; }
        }

        uint4 o;
        o.x = pack2(fmaxf(acc[0] + bLo.x, 0.f), fmaxf(acc[1] + bLo.y, 0.f));
        o.y = pack2(fmaxf(acc[2] + bLo.z, 0.f), fmaxf(acc[3] + bLo.w, 0.f));
        o.z = pack2(fmaxf(acc[4] + bHi.x, 0.f), fmaxf(acc[5] + bHi.y, 0.f));
        o.w = pack2(fmaxf(acc[6] + bHi.z, 0.f), fmaxf(acc[7] + bHi.w, 0.f));
        *(uint4*)(hout + (long)node * JK_DIM + cl * 8) = o;
    }
}

// ---------------------------------------------------------------------------
// FUSED layers 2/3 using A(hW) = (Ah)W:
//   h_out = relu( (A . h_prev) @ W + b )
// Per 64-node tile: 32 groups x 8 lanes aggregate h_prev rows (raw weighted
// sum, no bias) into LDS bf16 tile; then 4-wave MFMA with W^T; bias+ReLU in
// epilogue; write bf16 to hcat column block. Kills the lin round-trip and a
// kernel launch per layer.
// ---------------------------------------------------------------------------
__global__ __launch_bounds__(256) void agg_transform(
        const unsigned short* __restrict__ hprev,   // row stride JK_DIM
        const unsigned* __restrict__ ecsr,
        const int* __restrict__ off, const int* __restrict__ deg,
        const float* __restrict__ W, const float* __restrict__ bias,
        unsigned short* __restrict__ hout, int n) { // row stride JK_DIM
    __shared__ unsigned short Hs[64 * HP];   // aggregated tile, bf16
    __shared__ unsigned short Wt[64 * HP];   // W^T, bf16
    int tid = threadIdx.x;
    int row0 = blockIdx.x * 64;
    if (row0 >= n) return;
    // stage Wt (consumed after the sync below)
    for (int i = tid; i < 64 * 16; i += 256) {
        int k = i >> 4;
        int n4 = (i & 15) * 4;
        float4 v = *(const float4*)(W + (long)k * 64 + n4);
        Wt[(n4 + 0) * HP + k] = f2b(v.x);
        Wt[(n4 + 1) * HP + k] = f2b(v.y);
        Wt[(n4 + 2) * HP + k] = f2b(v.z);
        Wt[(n4 + 3) * HP + k] = f2b(v.w);
    }
    // aggregate: each 8-lane group handles 2 nodes of the 64-row tile
    int cl = tid & 7;
    int g0 = tid >> 3;
    for (int gi = 0; gi < 2; ++gi) {
        int lrow = g0 + gi * 32;
        int node = row0 + lrow;
        float acc[8];
#pragma unroll
        for (int i = 0; i < 8; ++i) acc[i] = 0.f;
        if (node < n) {
            int start = off[node];
            int cnt = deg[node];
            int s[8];
            float w[8];
#pragma unroll
            for (int t = 0; t < 8; ++t) {
                s[t] = 0; w[t] = 0.f;
                if (t < cnt) {
                    unsigned m = ecsr[start + t];
                    s[t] = (int)(m & 0xFFFFu);
                    w[t] = b2f((unsigned short)(m >> 16));
                }
            }
            for (int bb = 0; bb < cnt; bb += 8) {
                int s2[8];
                float w2[8];
#pragma unroll
                for (int t = 0; t < 8; ++t) {
                    int e = bb + 8 + t;
                    s2[t] = 0; w2[t] = 0.f;
                    if (e < cnt) {
                        unsigned m = ecsr[start + e];
                        s2[t] = (int)(m & 0xFFFFu);
                        w2[t] = b2f((unsigned short)(m >> 16));
                    }
                }
                uint4 u[8];
#pragma unroll
                for (int t = 0; t < 8; ++t)
                    u[t] = *(const uint4*)(hprev + (long)s[t] * JK_DIM + cl * 8);
#pragma unroll
                for (int t = 0; t < 8; ++t) {
                    acc[0] += blo(u[t].x) * w[t];
                    acc[1] += bhi(u[t].x) * w[t];
                    acc[2] += blo(u[t].y) * w[t];
                    acc[3] += bhi(u[t].y) * w[t];
                    acc[4] += blo(u[t].z) * w[t];
                    acc[5] += bhi(u[t].z) * w[t];
                    acc[6] += blo(u[t].w) * w[t];
                    acc[7] += bhi(u[t].w) * w[t];
                }
#pragma unroll
                for (int t = 0; t < 8; ++t) { s[t] = s2[t]; w[t] = w2[t]; }
            }
        }
        uint4 o;
        o.x = pack2(acc[0], acc[1]);
        o.y = pack2(acc[2], acc[3]);
        o.z = pack2(acc[4], acc[5]);
        o.w = pack2(acc[6], acc[7]);
        *(uint4*)(Hs + lrow * HP + cl * 8) = o;
    }
    __syncthreads();
    // MFMA: relu(Hs @ W + b)
    int wave = tid >> 6;
    int lane = tid & 63;
    int lr = lane & 15;
    int lk = (lane >> 4) * 8;
    f32x4 d[4];
#pragma unroll
    for (int nf = 0; nf < 4; ++nf) d[nf] = (f32x4){0.f, 0.f, 0.f, 0.f};
#pragma unroll
    for (int k0 = 0; k0 < 64; k0 += 32) {
        bf16x8 a = *(const bf16x8*)(Hs + (wave * 16 + lr) * HP + k0 + lk);
#pragma unroll
        for (int nf = 0; nf < 4; ++nf) {
            bf16x8 b = *(const bf16x8*)(Wt + (nf * 16 + lr) * HP + k0 + lk);
            d[nf] = __builtin_amdgcn_mfma_f32_16x16x32_bf16(a, b, d[nf], 0, 0, 0);
        }
    }
    int mbase = wave * 16 + (lane >> 4) * 4;
#pragma unroll
    for (int nf = 0; nf < 4; ++nf) {
        float bv = bias[nf * 16 + lr];
#pragma unroll
        for (int r = 0; r < 4; ++r) {
            int grow = row0 + mbase + r;
            if (grow < n)
                hout[(long)grow * JK_DIM + nf * 16 + lr] = f2b(fmaxf(d[nf][r] + bv, 0.f));
        }
    }
}

// ---------------------------------------------------------------------------
// Final: out[n,40](f32) = hcat[n,192](bf16) @ Wlin[192,40] + blin.
// ---------------------------------------------------------------------------
__global__ __launch_bounds__(256) void final_gemm(const unsigned short* __restrict__ hcat,
                                                  const float* __restrict__ Wt,
                                                  const float* __restrict__ b,
                                                  float* __restrict__ out, int n) {
    __shared__ float pool[OUT_DIM * W_PITCH];  // 31360 B
    int tid = threadIdx.x;
    for (int i = tid; i < OUT_DIM * 48; i += 256) {
        int c = i / 48;
        int q = (i - c * 48) * 4;
        *(float4*)(pool + c * W_PITCH + q) = *(const float4*)(Wt + (long)c * JK_DIM + q);
    }
    __syncthreads();

    int rg = tid >> 3;
    int cg = tid & 7;
    int c0 = cg * 5;
    int row0 = blockIdx.x * 64;
    int r0 = row0 + rg * 2;
    int ra = r0 < n ? r0 : n - 1;
    int rb = r0 + 1 < n ? r0 + 1 : n - 1;
    const unsigned short* ha = hcat + (long)ra * JK_DIM;
    const unsigned short* hb = hcat + (long)rb * JK_DIM;

    float acc[2][5];
#pragma unroll
    for (int r = 0; r < 2; ++r)
#pragma unroll
        for (int i = 0; i < 5; ++i) acc[r][i] = 0.f;

#pragma unroll 4
    for (int k = 0; k < JK_DIM; k += 4) {
        uint2 ua = *(const uint2*)(ha + k);
        uint2 ub = *(const uint2*)(hb + k);
        float4 va = make_float4(blo(ua.x), bhi(ua.x), blo(ua.y), bhi(ua.y));
        float4 vb = make_float4(blo(ub.x), bhi(ub.x), blo(ub.y), bhi(ub.y));
        float4 w0 = *(const float4*)(pool + (c0 + 0) * W_PITCH + k);
        float4 w1 = *(const float4*)(pool + (c0 + 1) * W_PITCH + k);
        float4 w2 = *(const float4*)(pool + (c0 + 2) * W_PITCH + k);
        float4 w3 = *(const float4*)(pool + (c0 + 3) * W_PITCH + k);
        float4 w4 = *(const float4*)(pool + (c0 + 4) * W_PITCH + k);
        acc[0][0] += va.x * w0.x + va.y * w0.y + va.z * w0.z + va.w * w0.w;
        acc[0][1] += va.x * w1.x + va.y * w1.y + va.z * w1.z + va.w * w1.w;
        acc[0][2] += va.x * w2.x + va.y * w2.y + va.z * w2.z + va.w * w2.w;
        acc[0][3] += va.x * w3.x + va.y * w3.y + va.z * w3.z + va.w * w3.w;
        acc[0][4] += va.x * w4.x + va.y * w4.y + va.z * w4.z + va.w * w4.w;
        acc[1][0] += vb.x * w0.x + vb.y * w0.y + vb.z * w0.z + vb.w * w0.w;
        acc[1][1] += vb.x * w1.x + vb.y * w1.y + vb.z * w1.z + vb.w * w1.w;
        acc[1][2] += vb.x * w2.x + vb.y * w2.y + vb.z * w2.z + vb.w * w2.w;
        acc[1][3] += vb.x * w3.x + vb.y * w3.y + vb.z * w3.z + vb.w * w3.w;
        acc[1][4] += vb.x * w4.x + vb.y * w4.y + vb.z * w4.z + vb.w * w4.w;
    }

    __syncthreads();
#pragma unroll
    for (int r = 0; r < 2; ++r)
#pragma unroll
        for (int i = 0; i < 5; ++i)
            pool[(rg * 2 + r) * FG_PITCH + c0 + i] = acc[r][i] + b[c0 + i];
    __syncthreads();

    if (row0 + 64 <= n) {
        for (int i = tid; i < 64 * OUT_DIM / 4; i += 256) {
            int f = i * 4;
            int row = f / OUT_DIM;
            int col = f - row * OUT_DIM;
            *(float4*)(out + (long)(row0 + row) * OUT_DIM + col) =
                *(const float4*)(pool + row * FG_PITCH + col);
        }
    } else {
        for (int i = tid; i < 64 * OUT_DIM; i += 256) {
            int row = i / OUT_DIM;
            int col = i - row * OUT_DIM;
            if (row0 + row < n)
                out[(long)(row0 + row) * OUT_DIM + col] = pool[row * FG_PITCH + col];
        }
    }
}

// ---------------------------------------------------------------------------
extern "C" void kernel_launch(void* const* d_in, const int* in_sizes, int n_in,
                              void* d_out, int out_size, void* d_ws, size_t ws_size,
                              hipStream_t stream) {
    const float* x    = (const float*)d_in[0];
    const int*   ei   = (const int*)d_in[1];
    const float* ew   = (const float*)d_in[2];
    const float* W1   = (const float*)d_in[3];
    const float* b1   = (const float*)d_in[4];
    const float* W2   = (const float*)d_in[5];
    const float* b2   = (const float*)d_in[6];
    const float* W3   = (const float*)d_in[7];
    const float* b3   = (const float*)d_in[8];
    const float* Wlin = (const float*)d_in[9];
    const float* blin = (const float*)d_in[10];
    float* out = (float*)d_out;

    const int N = in_sizes[0] / 128;   // 50000
    const int E = in_sizes[2];         // 800000
    const int* src = ei;
    const int* dst = ei + E;
    const int PART = (N + 7) / 8;      // 6250 nodes per XCD partition

    // Workspace: linb(bf16) | hcatb(bf16) | deg,off [N] | bsum | Wt | ecsr
    // rank[E] (ushort) ALIASES hcatb: rank dies before aggregate #1 writes hcatb.
    char* wsb = (char*)d_ws;
    unsigned short* linb  = (unsigned short*)wsb;   wsb += (long)N * HID * 2;
    unsigned short* hcatb = (unsigned short*)wsb;   wsb += (long)N * JK_DIM * 2;
    int* deg    = (int*)wsb;                        wsb += (long)N * 4;
    int* off    = (int*)wsb;                        wsb += (long)N * 4;
    int* bsum   = (int*)wsb;                        wsb += 256 * 4;
    float* Wt   = (float*)wsb;                      wsb += (long)JK_DIM * OUT_DIM * 4;
    unsigned* ecsr = (unsigned*)wsb;
    unsigned short* rank = hcatb;      // aliased
    int* gctr = bsum;                  // scan global counter

    dim3 blk(256);
    const int nblkN = (N + 255) / 256;     // 196
    dim3 gN(nblkN);
    dim3 gHist(8 * 104);                   // 8 partitions x 104 blocks
    const int nFill = ((E >> 2) + 255) / 256;  // 782 fill blocks (first)
    const int nGemm = (N + 63) / 64;           // 782 GEMM tiles (after)
    dim3 gFG(nFill + nGemm);
    dim3 gTile((N + 63) / 64);             // 782 tiles for agg_transform
    dim3 gAgg((N + 31) / 32);              // 8 nodes per wave
    dim3 gFin((N + 63) / 64);

    unsigned short* h1 = hcatb;            // columns [0,64)   of hcat[N,192]
    unsigned short* h2 = hcatb + HID;      // columns [64,128)
    unsigned short* h3 = hcatb + 2 * HID;  // columns [128,192)

    // ---- prep (zero deg+gctr, transpose Wlin), hist(+rank), fused scan ----
    prep<<<gN, blk, 0, stream>>>(deg, N, Wlin, Wt, gctr);
    hist_dst<<<gHist, blk, 0, stream>>>(dst, deg, rank, E, PART);
    scan_fused<<<gN, blk, 0, stream>>>(deg, off, gctr, N);

    // ---- fused atomic-free CSR fill + layer-1 MFMA GEMM ----
    fill_and_gemm<<<gFG, blk, 0, stream>>>(src, dst, ew, off, rank, ecsr, E,
                                           x, W1, linb, N, nFill);
    aggregate<<<gAgg, blk, 0, stream>>>(linb, ecsr, off, deg, b1, h1, N);

    // ---- layers 2/3: fused aggregate+transform (A(hW) = (Ah)W) ----
    agg_transform<<<gTile, blk, 0, stream>>>(h1, ecsr, off, deg, W2, b2, h2, N);
    agg_transform<<<gTile, blk, 0, stream>>>(h2, ecsr, off, deg, W3, b3, h3, N);

    // ---- JK linear ----
    final_gemm<<<gFin, blk, 0, stream>>>(hcatb, Wt, blin, out, N);
}